// Round 23
// baseline (27.435 us; speedup 1.0000x reference)
//
#include <hip/hip_runtime.h>
#include <stdint.h>

typedef __attribute__((ext_vector_type(8))) short short8;
typedef __attribute__((ext_vector_type(4))) float f32x4;

#define SEQ 256
#define NH 8

__device__ __forceinline__ uint32_t cvt_pk_bf16(float lo, float hi) {
  uint32_t r;
  asm("v_cvt_pk_bf16_f32 %0, %1, %2" : "=v"(r) : "v"(lo), "v"(hi));
  return r;
}

__device__ __forceinline__ short8 pack8(f32x4 a, f32x4 b) {
  union { uint32_t u[4]; short8 v; } t;
  t.u[0] = cvt_pk_bf16(a[0], a[1]);
  t.u[1] = cvt_pk_bf16(a[2], a[3]);
  t.u[2] = cvt_pk_bf16(b[0], b[1]);
  t.u[3] = cvt_pk_bf16(b[2], b[3]);
  return t.v;
}

// ---------------------------------------------------------------------------
// ONE fused kernel, r18 datapath, HALF-TILE for full occupancy.
// Block = (b, h, 32m x 64n), 512 thr (8 waves), 1024 blocks.
// LDS 39.4 KB -> 4 blocks/CU co-resident = 32 waves/CU (r18: 2 blocks, 16).
// Phase 0 (r18 staging patterns): sW1 <- w1[:,:,h]; sAp <- raw epos band
//   (96 rows: rl = m_loc-n_loc+63 in [0,94] + junk row 95); sAi (32) /
//   sAj (64) <- raw emb rows ([ebi|eci] / [ebj|ecj]).
// Phase 1: 12 wave-private tile-tasks (Ap x6, Ai x2, Aj x4) over 8 waves
//   (wave w: task w, and task 8+w if w<4). Per task: bf from sW1, af from
//   own raw tile, 2 MFMAs (r5-proven conventions), write D in-place
//   (within-wave read->write lockstep-safe; tiles disjoint across waves).
// Phase 2 (r18 verbatim, per-wave half: mb = w*4, single s-step, 4 groups).
// ---------------------------------------------------------------------------
__global__ __launch_bounds__(512, 4) void dis_att_fused(
    const float* __restrict__ attn, const int* __restrict__ bseq,
    const int* __restrict__ cseq, const float* __restrict__ epos,
    const float* __restrict__ ebi, const float* __restrict__ ebj,
    const float* __restrict__ eci, const float* __restrict__ ecj,
    const float* __restrict__ w1, const float* __restrict__ w2,
    const float* __restrict__ w3, float* __restrict__ out) {
  __shared__ float sW1[96][33];   // 12.4 KB
  __shared__ float sAp[96][36];   // 13.5 KB
  __shared__ float sAi[32][36];   //  4.5 KB
  __shared__ float sAj[64][36];   //  9.0 KB   total 39.4 KB
  int tid = threadIdx.x;
  int wg = blockIdx.x;                     // 1024 = b(4) h(8) mt(8) nt(4)
  int nt = wg & 3, mt = (wg >> 2) & 7, h = (wg >> 5) & 7, b = wg >> 8;
  int m0 = mt * 32, n0 = nt * 64;
  int f0 = m0 - n0 + 193;                  // f of band row 0 (1..417)
  int lane = tid & 63, w = tid >> 6;
  int lcol = lane & 15, kb = lane >> 4, k8 = kb * 8;
  f32x4 zero = {0.f, 0.f, 0.f, 0.f};

  // ---------------- phase 0: staging (r18 patterns) ----------------
#pragma unroll
  for (int i = 0; i < 6; ++i) {
    int idx = tid + 512 * i;               // p*32 + k, 3072 total
    sW1[idx >> 5][idx & 31] = w1[(idx >> 5) * 256 + (idx & 31) * 8 + h];
  }
  {
    int r = tid >> 3, q = tid & 7;         // r in [0,64)
    {                                      // sAp rows r and r+64 (<96)
      int f = f0 + r; if (f > 511) f = 511;
      *(f32x4*)&sAp[r][q * 4] = *(const f32x4*)(epos + (f * NH + h) * 32 + q * 4);
      if (r < 32) {
        int f2 = f0 + 64 + r; if (f2 > 511) f2 = 511;
        *(f32x4*)&sAp[64 + r][q * 4] =
            *(const f32x4*)(epos + (f2 * NH + h) * 32 + q * 4);
      }
    }
    int gmj = b * SEQ + n0 + r;
    if (q < 4) {
      int bj = bseq[gmj];
      *(f32x4*)&sAj[r][q * 4] = *(const f32x4*)(ebj + (bj * NH + h) * 16 + q * 4);
    } else {
      int cj = cseq[gmj];
      *(f32x4*)&sAj[r][q * 4] = *(const f32x4*)(ecj + (cj * NH + h) * 16 + (q - 4) * 4);
    }
    if (r < 32) {
      int gmi = b * SEQ + m0 + r;
      if (q < 4) {
        int bi = bseq[gmi];
        *(f32x4*)&sAi[r][q * 4] = *(const f32x4*)(ebi + (bi * NH + h) * 16 + q * 4);
      } else {
        int ci = cseq[gmi];
        *(f32x4*)&sAi[r][q * 4] = *(const f32x4*)(eci + (ci * NH + h) * 16 + (q - 4) * 4);
      }
    }
  }
  __syncthreads();

  // ---------------- phase 1: 12 wave-private tile tasks ----------------
#pragma unroll
  for (int tt = 0; tt < 2; ++tt) {
    int task = w + tt * 8;
    if (task < 12) {
      int type = task < 6 ? 0 : (task < 8 ? 1 : 2);   // Ap / Ai / Aj
      int tile = task < 6 ? task : (task < 8 ? task - 6 : task - 8);
      int p0 = (type == 0) ? k8
             : (type == 1) ? ((kb < 2 ? 32 : 48) + k8)
                           : ((kb < 2 ? 48 : 64) + k8);
      short8 bf[2];
#pragma unroll
      for (int kt = 0; kt < 2; ++kt) {
        union { uint32_t u[4]; short8 v; } t;
#pragma unroll
        for (int r = 0; r < 4; ++r)
          t.u[r] = cvt_pk_bf16(sW1[p0 + 2 * r][kt * 16 + lcol],
                               sW1[p0 + 2 * r + 1][kt * 16 + lcol]);
        bf[kt] = t.v;
      }
      int arow = tile * 16 + lcol;
      const float* base = (type == 0) ? &sAp[arow][0]
                        : (type == 1) ? &sAi[arow][0] : &sAj[arow][0];
      short8 af = pack8(*(const f32x4*)(base + k8),
                        *(const f32x4*)(base + k8 + 4));
#pragma unroll
      for (int kt = 0; kt < 2; ++kt) {
        f32x4 d = __builtin_amdgcn_mfma_f32_16x16x32_bf16(af, bf[kt], zero, 0, 0, 0);
#pragma unroll
        for (int r = 0; r < 4; ++r) {
          int prow = tile * 16 + kb * 4 + r, pcol = kt * 16 + lcol;
          if (type == 0)      sAp[prow][pcol] = d[r];
          else if (type == 1) sAi[prow][pcol] = d[r];
          else                sAj[prow][pcol] = d[r];
        }
      }
    }
  }
  __syncthreads();

  // ---------------- phase 2: main compute (r18 verbatim, half) ----------
  union { uint32_t u[4]; short8 v; } w2f;  // A = w2^T: row=lcol, k=k8..k8+7
#pragma unroll
  for (int r = 0; r < 4; ++r) {
    float lo = w2[(k8 + 2 * r) * 128 + lcol * 8 + h];
    float hi = w2[(k8 + 2 * r + 1) * 128 + lcol * 8 + h];
    w2f.u[r] = cvt_pk_bf16(lo, hi);
  }
  float w3v[4];
#pragma unroll
  for (int r = 0; r < 4; ++r) w3v[r] = w3[(kb * 4 + r) * 8 + h];

  f32x4 ajA[4], ajB[4];
#pragma unroll
  for (int ng = 0; ng < 4; ++ng) {
    int nl = ng * 16 + lcol;
    ajA[ng] = *(const f32x4*)&sAj[nl][k8];
    ajB[ng] = *(const f32x4*)&sAj[nl][k8 + 4];
  }

  const float* attn_b = attn + (b * NH + h) * SEQ * SEQ;
  float* out_b = out + (b * NH + h) * SEQ * SEQ;
  int bit4 = kb & 1, bit5 = kb & 2;

  {
    int mb = w * 4;                        // wave owns m rows mb..mb+3
    float av[4];
    int idxs[4];
#pragma unroll
    for (int ng = 0; ng < 4; ++ng) {
      idxs[ng] = (m0 + mb + kb) * SEQ + n0 + ng * 16 + lcol;
      av[ng] = attn_b[idxs[ng]];
    }
    f32x4 aiA[4], aiB[4];
#pragma unroll
    for (int mi = 0; mi < 4; ++mi) {
      aiA[mi] = *(const f32x4*)&sAi[mb + mi][k8];
      aiB[mi] = *(const f32x4*)&sAi[mb + mi][k8 + 4];
    }
#pragma unroll
    for (int ng = 0; ng < 4; ++ng) {
      int nl = ng * 16 + lcol;
      f32x4 pA[4], pB[4];
#pragma unroll
      for (int mi = 0; mi < 4; ++mi) {
        int rl = mb + mi - nl + 63;
        pA[mi] = *(const f32x4*)&sAp[rl][k8];
        pB[mi] = *(const f32x4*)&sAp[rl][k8 + 4];
      }
      __builtin_amdgcn_sched_barrier(0);
      float part[4];
#pragma unroll
      for (int mi = 0; mi < 4; ++mi) {
        f32x4 s0 = pA[mi] + aiA[mi] + ajA[ng];
        f32x4 s1 = pB[mi] + aiB[mi] + ajB[ng];
        union { uint32_t u[4]; short8 v; } ef;
        ef.u[0] = cvt_pk_bf16(fmaxf(s0[0], 0.f), fmaxf(s0[1], 0.f));
        ef.u[1] = cvt_pk_bf16(fmaxf(s0[2], 0.f), fmaxf(s0[3], 0.f));
        ef.u[2] = cvt_pk_bf16(fmaxf(s1[0], 0.f), fmaxf(s1[1], 0.f));
        ef.u[3] = cvt_pk_bf16(fmaxf(s1[2], 0.f), fmaxf(s1[3], 0.f));
        f32x4 d = __builtin_amdgcn_mfma_f32_16x16x32_bf16(w2f.v, ef.v, zero, 0, 0, 0);
        part[mi] = fmaxf(d[0], 0.f) * w3v[0] + fmaxf(d[1], 0.f) * w3v[1] +
                   fmaxf(d[2], 0.f) * w3v[2] + fmaxf(d[3], 0.f) * w3v[3];
      }
      float mineA = bit4 ? part[1] : part[0];
      float sendA = bit4 ? part[0] : part[1];
      float mineB = bit4 ? part[3] : part[2];
      float sendB = bit4 ? part[2] : part[3];
      mineA += __shfl_xor(sendA, 16, 64);
      mineB += __shfl_xor(sendB, 16, 64);
      float keep = bit5 ? mineB : mineA;
      float send = bit5 ? mineA : mineB;
      float res = keep + __shfl_xor(send, 32, 64);
      out_b[idxs[ng]] = av[ng] + res;
    }
  }
}

extern "C" void kernel_launch(void* const* d_in, const int* in_sizes, int n_in,
                              void* d_out, int out_size, void* d_ws, size_t ws_size,
                              hipStream_t stream) {
  const float* attn = (const float*)d_in[0];
  const int* bseq   = (const int*)d_in[1];
  const int* cseq   = (const int*)d_in[2];
  const float* epos = (const float*)d_in[3];
  const float* ebi  = (const float*)d_in[4];
  const float* ebj  = (const float*)d_in[5];
  const float* eci  = (const float*)d_in[6];
  const float* ecj  = (const float*)d_in[7];
  const float* w1   = (const float*)d_in[8];
  const float* w2   = (const float*)d_in[9];
  const float* w3   = (const float*)d_in[10];
  float* out = (float*)d_out;

  hipLaunchKernelGGL(dis_att_fused, dim3(1024), dim3(512), 0, stream,
                     attn, bseq, cseq, epos, ebi, ebj, eci, ecj, w1, w2, w3, out);
}

// Round 24
// 22.046 us; speedup vs baseline: 1.2444x; 1.2444x over previous
//
#include <hip/hip_runtime.h>
#include <stdint.h>

typedef __attribute__((ext_vector_type(8))) short short8;
typedef __attribute__((ext_vector_type(4))) float f32x4;

#define SEQ 256
#define NH 8

__device__ __forceinline__ uint32_t cvt_pk_bf16(float lo, float hi) {
  uint32_t r;
  asm("v_cvt_pk_bf16_f32 %0, %1, %2" : "=v"(r) : "v"(lo), "v"(hi));
  return r;
}

__device__ __forceinline__ short8 pack8(f32x4 a, f32x4 b) {
  union { uint32_t u[4]; short8 v; } t;
  t.u[0] = cvt_pk_bf16(a[0], a[1]);
  t.u[1] = cvt_pk_bf16(a[2], a[3]);
  t.u[2] = cvt_pk_bf16(b[0], b[1]);
  t.u[3] = cvt_pk_bf16(b[2], b[3]);
  return t.v;
}

// ---------------------------------------------------------------------------
// ONE fused kernel (r18 = session best, 22.25us). Block = (b,h,64m x 64n),
// 512 thr (8 waves), 512 blocks.
// Phase 0: coalesced staging: sW1 <- w1[:,:,h] (12.7 KB); sAp <- raw epos
//   band (128 rows x 32, f32x4 8 thr/row); sAi/sAj <- raw emb rows
//   ([ebi|eci] / [ebj|ecj], one 64B row-half per 4 threads).
// Phase 1: A-fragments via ds_read from raw LDS; B-fragments from sW1;
//   MFMA into regs (r5-validated conventions); barrier; write D IN-PLACE.
// Phase 2: batched pA/pB chains, e1=relu(Ap+Ai+Aj)->bf16, mfma(A=w2^T),
//   relu-dot w3, 3-shuffle butterfly reduce, coalesced attn-add store.
// ---------------------------------------------------------------------------
__global__ __launch_bounds__(512, 4) void dis_att_fused(
    const float* __restrict__ attn, const int* __restrict__ bseq,
    const int* __restrict__ cseq, const float* __restrict__ epos,
    const float* __restrict__ ebi, const float* __restrict__ ebj,
    const float* __restrict__ eci, const float* __restrict__ ecj,
    const float* __restrict__ w1, const float* __restrict__ w2,
    const float* __restrict__ w3, float* __restrict__ out) {
  __shared__ float sW1[96][33];
  __shared__ float sAp[128][36];
  __shared__ float sAi[64][36];
  __shared__ float sAj[64][36];
  int tid = threadIdx.x;
  int wg = blockIdx.x;                     // 512 = b(4) h(8) mt(4) nt(4)
  int nt = wg & 3, mt = (wg >> 2) & 3, h = (wg >> 4) & 7, b = wg >> 7;
  int m0 = mt * 64, n0 = nt * 64;
  int f0 = m0 - n0 + 193;                  // global f of sAp row 0
  int lane = tid & 63, w = tid >> 6;
  int lcol = lane & 15, kb = lane >> 4, k8 = kb * 8;
  f32x4 zero = {0.f, 0.f, 0.f, 0.f};

  // ---------------- phase 0: coalesced staging ----------------
#pragma unroll
  for (int i = 0; i < 6; ++i) {
    int idx = tid + 512 * i;               // p*32 + k, 3072 total
    sW1[idx >> 5][idx & 31] = w1[(idx >> 5) * 256 + (idx & 31) * 8 + h];
  }
  {
    int r = tid >> 3, q = tid & 7;
#pragma unroll
    for (int p = 0; p < 2; ++p) {
      int row = r + 64 * p;
      int f = f0 + row; if (f > 511) f = 511;
      *(f32x4*)&sAp[row][q * 4] = *(const f32x4*)(epos + (f * NH + h) * 32 + q * 4);
    }
    int gmi = b * SEQ + m0 + r, gmj = b * SEQ + n0 + r;
    if (q < 4) {
      int bi = bseq[gmi], bj = bseq[gmj];
      *(f32x4*)&sAi[r][q * 4] = *(const f32x4*)(ebi + (bi * NH + h) * 16 + q * 4);
      *(f32x4*)&sAj[r][q * 4] = *(const f32x4*)(ebj + (bj * NH + h) * 16 + q * 4);
    } else {
      int ci = cseq[gmi], cj = cseq[gmj];
      *(f32x4*)&sAi[r][q * 4] = *(const f32x4*)(eci + (ci * NH + h) * 16 + (q - 4) * 4);
      *(f32x4*)&sAj[r][q * 4] = *(const f32x4*)(ecj + (cj * NH + h) * 16 + (q - 4) * 4);
    }
  }
  __syncthreads();

  // ---------------- phase 1a: fragment reads (LDS -> regs) ----------------
  short8 af[2], bf[2];
  if (w < 4) {                             // Apos: tiles {w, w+4}
#pragma unroll
    for (int kt = 0; kt < 2; ++kt) {
      union { uint32_t u[4]; short8 v; } t;
#pragma unroll
      for (int r = 0; r < 4; ++r)
        t.u[r] = cvt_pk_bf16(sW1[k8 + 2 * r][kt * 16 + lcol],
                             sW1[k8 + 2 * r + 1][kt * 16 + lcol]);
      bf[kt] = t.v;
    }
#pragma unroll
    for (int t = 0; t < 2; ++t) {
      int row = (w + t * 4) * 16 + lcol;
      af[t] = pack8(*(const f32x4*)&sAp[row][k8],
                    *(const f32x4*)&sAp[row][k8 + 4]);
    }
  } else {                                 // Ai (waves 4,5) / Aj (waves 6,7)
    int isI = w < 6;
    int p0 = isI ? ((kb < 2 ? 32 : 48) + k8)
                 : ((kb < 2 ? 48 : 64) + k8);
#pragma unroll
    for (int kt = 0; kt < 2; ++kt) {
      union { uint32_t u[4]; short8 v; } t;
#pragma unroll
      for (int r = 0; r < 4; ++r)
        t.u[r] = cvt_pk_bf16(sW1[p0 + 2 * r][kt * 16 + lcol],
                             sW1[p0 + 2 * r + 1][kt * 16 + lcol]);
      bf[kt] = t.v;
    }
    int w2_ = isI ? (w - 4) : (w - 6);
#pragma unroll
    for (int t = 0; t < 2; ++t) {
      int row = (w2_ * 2 + t) * 16 + lcol;
      const float* base = isI ? &sAi[row][0] : &sAj[row][0];
      af[t] = pack8(*(const f32x4*)(base + k8), *(const f32x4*)(base + k8 + 4));
    }
  }
  __syncthreads();                         // all raw reads done

  // ---------------- phase 1b: MFMA + in-place writes ----------------
#pragma unroll
  for (int t = 0; t < 2; ++t) {
#pragma unroll
    for (int kt = 0; kt < 2; ++kt) {
      f32x4 d = __builtin_amdgcn_mfma_f32_16x16x32_bf16(af[t], bf[kt], zero, 0, 0, 0);
      if (w < 4) {
        int mt_ = w + t * 4;
#pragma unroll
        for (int r = 0; r < 4; ++r)
          sAp[mt_ * 16 + kb * 4 + r][kt * 16 + lcol] = d[r];
      } else {
        int isI = w < 6;
        int mt_ = (isI ? (w - 4) : (w - 6)) * 2 + t;
#pragma unroll
        for (int r = 0; r < 4; ++r) {
          float* T = isI ? &sAi[mt_ * 16 + kb * 4 + r][kt * 16 + lcol]
                         : &sAj[mt_ * 16 + kb * 4 + r][kt * 16 + lcol];
          *T = d[r];
        }
      }
    }
  }
  __syncthreads();

  // ---------------- phase 2: main compute (validated r7/r12) ----------------
  union { uint32_t u[4]; short8 v; } w2f;  // A = w2^T: row=lcol, k=k8..k8+7
#pragma unroll
  for (int r = 0; r < 4; ++r) {
    float lo = w2[(k8 + 2 * r) * 128 + lcol * 8 + h];
    float hi = w2[(k8 + 2 * r + 1) * 128 + lcol * 8 + h];
    w2f.u[r] = cvt_pk_bf16(lo, hi);
  }
  float w3v[4];
#pragma unroll
  for (int r = 0; r < 4; ++r) w3v[r] = w3[(kb * 4 + r) * 8 + h];

  f32x4 ajA[4], ajB[4];
#pragma unroll
  for (int ng = 0; ng < 4; ++ng) {
    int nl = ng * 16 + lcol;
    ajA[ng] = *(const f32x4*)&sAj[nl][k8];
    ajB[ng] = *(const f32x4*)&sAj[nl][k8 + 4];
  }

  const float* attn_b = attn + (b * NH + h) * SEQ * SEQ;
  float* out_b = out + (b * NH + h) * SEQ * SEQ;
  int bit4 = kb & 1, bit5 = kb & 2;

#pragma unroll
  for (int s = 0; s < 2; ++s) {
    int mb = w * 8 + s * 4;
    float av[4];
    int idxs[4];
#pragma unroll
    for (int ng = 0; ng < 4; ++ng) {
      idxs[ng] = (m0 + mb + kb) * SEQ + n0 + ng * 16 + lcol;
      av[ng] = attn_b[idxs[ng]];
    }
    f32x4 aiA[4], aiB[4];
#pragma unroll
    for (int mi = 0; mi < 4; ++mi) {
      aiA[mi] = *(const f32x4*)&sAi[mb + mi][k8];
      aiB[mi] = *(const f32x4*)&sAi[mb + mi][k8 + 4];
    }
#pragma unroll
    for (int ng = 0; ng < 4; ++ng) {
      int nl = ng * 16 + lcol;
      f32x4 pA[4], pB[4];
#pragma unroll
      for (int mi = 0; mi < 4; ++mi) {
        int rl = mb + mi - nl + 63;
        pA[mi] = *(const f32x4*)&sAp[rl][k8];
        pB[mi] = *(const f32x4*)&sAp[rl][k8 + 4];
      }
      __builtin_amdgcn_sched_barrier(0);
      float part[4];
#pragma unroll
      for (int mi = 0; mi < 4; ++mi) {
        f32x4 s0 = pA[mi] + aiA[mi] + ajA[ng];
        f32x4 s1 = pB[mi] + aiB[mi] + ajB[ng];
        union { uint32_t u[4]; short8 v; } ef;
        ef.u[0] = cvt_pk_bf16(fmaxf(s0[0], 0.f), fmaxf(s0[1], 0.f));
        ef.u[1] = cvt_pk_bf16(fmaxf(s0[2], 0.f), fmaxf(s0[3], 0.f));
        ef.u[2] = cvt_pk_bf16(fmaxf(s1[0], 0.f), fmaxf(s1[1], 0.f));
        ef.u[3] = cvt_pk_bf16(fmaxf(s1[2], 0.f), fmaxf(s1[3], 0.f));
        f32x4 d = __builtin_amdgcn_mfma_f32_16x16x32_bf16(w2f.v, ef.v, zero, 0, 0, 0);
        part[mi] = fmaxf(d[0], 0.f) * w3v[0] + fmaxf(d[1], 0.f) * w3v[1] +
                   fmaxf(d[2], 0.f) * w3v[2] + fmaxf(d[3], 0.f) * w3v[3];
      }
      float mineA = bit4 ? part[1] : part[0];
      float sendA = bit4 ? part[0] : part[1];
      float mineB = bit4 ? part[3] : part[2];
      float sendB = bit4 ? part[2] : part[3];
      mineA += __shfl_xor(sendA, 16, 64);
      mineB += __shfl_xor(sendB, 16, 64);
      float keep = bit5 ? mineB : mineA;
      float send = bit5 ? mineA : mineB;
      float res = keep + __shfl_xor(send, 32, 64);
      out_b[idxs[ng]] = av[ng] + res;
    }
  }
}

extern "C" void kernel_launch(void* const* d_in, const int* in_sizes, int n_in,
                              void* d_out, int out_size, void* d_ws, size_t ws_size,
                              hipStream_t stream) {
  const float* attn = (const float*)d_in[0];
  const int* bseq   = (const int*)d_in[1];
  const int* cseq   = (const int*)d_in[2];
  const float* epos = (const float*)d_in[3];
  const float* ebi  = (const float*)d_in[4];
  const float* ebj  = (const float*)d_in[5];
  const float* eci  = (const float*)d_in[6];
  const float* ecj  = (const float*)d_in[7];
  const float* w1   = (const float*)d_in[8];
  const float* w2   = (const float*)d_in[9];
  const float* w3   = (const float*)d_in[10];
  float* out = (float*)d_out;

  hipLaunchKernelGGL(dis_att_fused, dim3(512), dim3(512), 0, stream,
                     attn, bseq, cseq, epos, ebi, ebj, eci, ecj, w1, w2, w3, out);
}